// Round 3
// baseline (122.448 us; speedup 1.0000x reference)
//
#include <hip/hip_runtime.h>

// Problem constants
constexpr int T_    = 4096;
constexpr int DH_   = 128;
constexpr int NB_   = 32;    // buckets
constexpr int BSZ_  = 128;   // bucket size
constexpr int HH_   = 4;     // H/2 (rotated heads start here)
constexpr int H_    = 8;
constexpr int BH_   = 32;    // B*H

typedef __attribute__((ext_vector_type(8))) short short8;
typedef __attribute__((ext_vector_type(4))) float f32x4;

__device__ __forceinline__ unsigned short f2bf(float f) {
  // round-to-nearest-even fp32 -> bf16 (finite inputs only)
  unsigned int u = __float_as_uint(f);
  unsigned int r = (u + 0x7FFFu + ((u >> 16) & 1u)) >> 16;
  return (unsigned short)r;
}

// ---------------- Kernel A1: per-bucket column sums + first row of each bucket ----------
__global__ __launch_bounds__(256)
void k_bucket_sums(const float* __restrict__ k,
                   float* __restrict__ bucketsum,
                   float* __restrict__ firstrow) {
  __shared__ float4 red[8][32];
  int blk = blockIdx.x;           // (b*H + h)*NB + u
  int u = blk & (NB_ - 1);
  int bh = blk >> 5;
  int h = bh & (H_ - 1);
  bool rot = (h >= HH_);
  int tid = threadIdx.x;
  int rq = tid >> 5;              // 0..7
  int l  = tid & 31;              // 0..31
  int d0 = l * 4;
  const float* kb = k + (size_t)bh * T_ * DH_;

  float4 s = {0.f, 0.f, 0.f, 0.f};
  float4 first = {0.f, 0.f, 0.f, 0.f};
  #pragma unroll
  for (int it = 0; it < 16; ++it) {
    int i = it * 8 + rq;
    int t = u * BSZ_ + i;
    if (rot) t = (t + (BSZ_ - 1)) & (T_ - 1);
    float4 a = *(const float4*)(kb + (size_t)t * DH_ + d0);
    s.x += a.x; s.y += a.y; s.z += a.z; s.w += a.w;
    if (it == 0 && rq == 0) first = a;
  }
  red[rq][l] = s;
  __syncthreads();
  if (rq == 0) {
    float4 acc = {0.f, 0.f, 0.f, 0.f};
    #pragma unroll
    for (int j = 0; j < 8; ++j) {
      float4 a = red[j][l];
      acc.x += a.x; acc.y += a.y; acc.z += a.z; acc.w += a.w;
    }
    *(float4*)(bucketsum + (size_t)blk * DH_ + d0) = acc;
    *(float4*)(firstrow  + (size_t)blk * DH_ + d0) = first;
  }
}

// ---------------- Kernel A2: routing matrix R -> (scale, idx) packed float2 -------------
__global__ __launch_bounds__(256)
void k_routing(const float* __restrict__ W,
               const float* __restrict__ bucketsum,
               const float* __restrict__ firstrow,
               float2* __restrict__ scIdx) {
  __shared__ float Wl[2 * DH_ * NB_];      // [e][v] row-major, 8192 floats
  __shared__ float Xl[NB_][2 * DH_ + 1];   // padded
  __shared__ float Rl[NB_][36];            // 36-float rows: 16B aligned
  int bh = blockIdx.x;
  int h = bh & (H_ - 1);
  int tid = threadIdx.x;                   // 256 threads

  const float4* Wg = (const float4*)(W + (size_t)h * 2 * DH_ * NB_);
  #pragma unroll
  for (int rep = 0; rep < 8; ++rep)
    ((float4*)Wl)[tid + rep * 256] = Wg[tid + rep * 256];

  if (tid < DH_) {
    int d = tid;
    float S = 0.f;
    for (int u = 0; u < NB_; ++u) {
      float fr = firstrow [((size_t)bh * NB_ + u) * DH_ + d];
      float bs = bucketsum[((size_t)bh * NB_ + u) * DH_ + d];
      Xl[u][d]        = (S + fr) / (float)(u * BSZ_ + 1);
      Xl[u][DH_ + d]  = fr;
      S += bs;
    }
  }
  __syncthreads();

  {
    int u = tid >> 3;
    int vg = tid & 7;
    float4 racc = {0.f, 0.f, 0.f, 0.f};
    for (int e = 0; e < 2 * DH_; ++e) {
      float xv = Xl[u][e];
      float4 wv = *(const float4*)(Wl + e * NB_ + vg * 4);
      racc.x += xv * wv.x; racc.y += xv * wv.y;
      racc.z += xv * wv.z; racc.w += xv * wv.w;
    }
    racc.x = (racc.x > 0.f) ? racc.x : 0.01f * racc.x;
    racc.y = (racc.y > 0.f) ? racc.y : 0.01f * racc.y;
    racc.z = (racc.z > 0.f) ? racc.z : 0.01f * racc.z;
    racc.w = (racc.w > 0.f) ? racc.w : 0.01f * racc.w;
    *(float4*)(&Rl[u][vg * 4]) = racc;
  }
  __syncthreads();

  if (tid < NB_) {
    int u = tid;
    float m = -3.4e38f;
    float r[NB_];
    #pragma unroll
    for (int v = 0; v < NB_; ++v) { r[v] = Rl[u][v]; m = fmaxf(m, r[v]); }
    float Z = 0.f;
    #pragma unroll
    for (int v = 0; v < NB_; ++v) Z += expf(r[v] - m);
    float best = -3.4e38f; int bi = 0;
    for (int v = 0; v < u; ++v) {        // tril(-1): only v < u survive
      if (r[v] > best) { best = r[v]; bi = v; }
    }
    float sc = (u == 0) ? 0.f : expf(best - m) / Z;
    int  idx = (u == 0) ? 0 : bi;
    scIdx[bh * NB_ + u] = make_float2(sc, __int_as_float(idx));
  }
}

// ---------------- Kernel B: bucketed attention, 80KB LDS, quarter-pipelined V ----------
// L0 32KB: K1 -> P quarters (a=0, b=+8192). L1 32KB: K2 -> VTq1(0), VTq2(+8192).
// L2 16KB: VTq0 -> VTq3. Scale sc folded into scores + P (staging is pure fp32->bf16).
__global__ __launch_bounds__(512, 4)
void k_attn(const float* __restrict__ q, const float* __restrict__ k,
            const float* __restrict__ v, const float2* __restrict__ scIdx,
            float* __restrict__ out) {
  __shared__ __align__(16) unsigned short L0[128 * 128];
  __shared__ __align__(16) unsigned short L1[128 * 128];
  __shared__ __align__(16) unsigned short L2[64 * 128];

  int blk0 = blockIdx.x;
  int blk  = ((blk0 & 7) << 7) | (blk0 >> 3);  // XCD-chunked swizzle (1024 = 8*128)
  int u  = blk & (NB_ - 1);
  int bh = blk >> 5;
  int h  = bh & (H_ - 1);
  bool rot = (h >= HH_);
  float2 si = scIdx[bh * NB_ + u];
  float sc = si.x;
  int  src = __float_as_int(si.y);
  const size_t base = (size_t)bh * T_ * DH_;

  int tid  = threadIdx.x;
  int lane = tid & 63;
  int w    = tid >> 6;        // wave 0..7, owns q-rows [16w, 16w+16)
  int g    = lane >> 4;       // 0..3
  int c    = lane & 15;       // 0..15

  // ---- Q fragments ----
  short8 qf[4];
  {
    int t = u * BSZ_ + 16 * w + c;
    if (rot) t = (t + (BSZ_ - 1)) & (T_ - 1);
    const float* qrow = q + base + (size_t)t * DH_;
    #pragma unroll
    for (int kt = 0; kt < 4; ++kt) {
      f32x4 a = *(const f32x4*)(qrow + kt * 32 + g * 8);
      f32x4 b = *(const f32x4*)(qrow + kt * 32 + g * 8 + 4);
      short8 f;
      f[0]=(short)f2bf(a[0]); f[1]=(short)f2bf(a[1]); f[2]=(short)f2bf(a[2]); f[3]=(short)f2bf(a[3]);
      f[4]=(short)f2bf(b[0]); f[5]=(short)f2bf(b[1]); f[6]=(short)f2bf(b[2]); f[7]=(short)f2bf(b[3]);
      qf[kt] = f;
    }
  }

  // ---- Stage K halves (pure convert, no scale): K1->L0, K2->L1 ----
  #pragma unroll
  for (int rep = 0; rep < 16; ++rep) {
    int chunk = tid + rep * 512;          // 8192 chunks of 4 floats
    int jr = chunk >> 5;                  // 0..255
    int c0 = (chunk & 31) * 4;
    int t = (jr < BSZ_) ? (src * BSZ_ + jr) : (u * BSZ_ + (jr - BSZ_));
    if (rot) t = (t + (BSZ_ - 1)) & (T_ - 1);
    f32x4 a = *(const f32x4*)(k + base + (size_t)t * DH_ + c0);
    ushort4 wv;
    wv.x=f2bf(a[0]); wv.y=f2bf(a[1]); wv.z=f2bf(a[2]); wv.w=f2bf(a[3]);
    unsigned short* Rg = (jr < BSZ_) ? L0 : L1;
    int row = jr & 127;
    *(ushort4*)((char*)Rg + row * 256 + ((c0 * 2) ^ ((row & 15) << 4))) = wv;
  }

  // ---- V quarter load/write helpers (quarter = 64 j-rows, [128 d][64 j] bf16, 128B rows)
  int vdt = tid & 31, vj4 = tid >> 5;     // 32 d-tiles x 16 j-tiles
  int vd0 = vdt * 4, vjl0 = vj4 * 4;

  auto vt_load = [&](int qtr, f32x4* rr) {
    #pragma unroll
    for (int jj = 0; jj < 4; ++jj) {
      int jgl = qtr * 64 + vjl0 + jj;     // global j (0..255)
      int t = (jgl < BSZ_) ? (src * BSZ_ + jgl) : (u * BSZ_ + (jgl - BSZ_));
      if (rot) t = (t + (BSZ_ - 1)) & (T_ - 1);
      rr[jj] = *(const f32x4*)(v + base + (size_t)t * DH_ + vd0);
    }
  };
  auto vt_write = [&](const f32x4* rr, unsigned short* Rg) {
    #pragma unroll
    for (int m = 0; m < 4; ++m) {
      ushort4 wv;
      wv.x=f2bf(rr[0][m]); wv.y=f2bf(rr[1][m]); wv.z=f2bf(rr[2][m]); wv.w=f2bf(rr[3][m]);
      int row = vd0 + m;
      *(ushort4*)((char*)Rg + row * 128 + ((vjl0 * 2) ^ ((row & 7) << 4))) = wv;
    }
  };

  f32x4 rr0[4];
  vt_load(0, rr0); vt_write(rr0, L2);     // VTq0 staged at t=0
  f32x4 rq1[4];
  vt_load(1, rq1);                        // VTq1 in flight under QK

  __syncthreads();   // S1

  // ---- QK^T ----
  f32x4 acc[16];
  #pragma unroll
  for (int jt = 0; jt < 16; ++jt) acc[jt] = f32x4{0.f, 0.f, 0.f, 0.f};
  __builtin_amdgcn_s_setprio(1);
  #pragma unroll
  for (int kt = 0; kt < 4; ++kt) {
    #pragma unroll
    for (int jt = 0; jt < 16; ++jt) {
      const unsigned short* Rg = (jt < 8) ? L0 : L1;
      int row = (jt & 7) * 16 + c;
      short8 bfr = *(const short8*)((const char*)Rg + row * 256 + ((kt * 64 + g * 16) ^ ((row & 15) << 4)));
      acc[jt] = __builtin_amdgcn_mfma_f32_16x16x32_bf16(qf[kt], bfr, acc[jt], 0, 0, 0);
    }
  }
  __builtin_amdgcn_s_setprio(0);

  __syncthreads();   // S2 (K reads done; L1 free)

  vt_write(rq1, L1);                      // VTq1 -> L1a
  {
    f32x4 rq2[4];
    vt_load(2, rq2); vt_write(rq2, L1 + 64 * 128);   // VTq2 -> L1b (latency under softmax)
  }
  f32x4 rq3[4];
  vt_load(3, rq3);                        // VTq3 held in regs

  // ---- softmax (sc folded into score scale; log2e folded for exp2) ----
  const bool lastrot = rot && (u == NB_ - 1);
  const float LOG2E = 1.44269504f;
  float scale1 = 0.03125f * LOG2E * sc;   // j < 128 columns (src bucket)
  float scale2 = 0.03125f * LOG2E;
  #pragma unroll
  for (int r = 0; r < 4; ++r) {
    int i = 16 * w + 4 * g + r;
    float mx = -3.4e38f;
    #pragma unroll
    for (int jt = 0; jt < 16; ++jt) {
      int j = jt * 16 + c;
      float s = acc[jt][r] * ((jt < 8) ? scale1 : scale2);
      bool causal = (j < BSZ_) || (i >= j - BSZ_);
      bool vis = lastrot ? (causal && !((j <= BSZ_) && (i > 0))) : causal;
      s = vis ? s : -3.4e38f;
      acc[jt][r] = s;
      mx = fmaxf(mx, s);
    }
    mx = fmaxf(mx, __shfl_xor(mx, 1));
    mx = fmaxf(mx, __shfl_xor(mx, 2));
    mx = fmaxf(mx, __shfl_xor(mx, 4));
    mx = fmaxf(mx, __shfl_xor(mx, 8));
    float zs = 0.f;
    #pragma unroll
    for (int jt = 0; jt < 16; ++jt) {
      float p = exp2f(acc[jt][r] - mx);
      acc[jt][r] = p;
      zs += p;
    }
    zs += __shfl_xor(zs, 1);
    zs += __shfl_xor(zs, 2);
    zs += __shfl_xor(zs, 4);
    zs += __shfl_xor(zs, 8);
    float rz = 1.f / zs;
    float rzs = rz * sc;                  // P columns j<128 carry sc into PV
    #pragma unroll
    for (int jt = 0; jt < 4; ++jt) {
      int jl = jt * 16 + c;
      *(unsigned short*)((char*)L0 + i * 128 + ((jl * 2) ^ ((i & 7) << 4))) = f2bf(acc[jt][r] * rzs);
    }
    #pragma unroll
    for (int jt = 4; jt < 8; ++jt) {
      int jl = (jt - 4) * 16 + c;
      *(unsigned short*)((char*)(L0 + 64 * 128) + i * 128 + ((jl * 2) ^ ((i & 7) << 4))) = f2bf(acc[jt][r] * rzs);
    }
    #pragma unroll
    for (int jt = 8; jt < 16; ++jt) acc[jt][r] *= rz;
  }

  // ---- PV quarters (P reads are wave-local: no barriers around P) ----
  f32x4 o[8];
  #pragma unroll
  for (int nt = 0; nt < 8; ++nt) o[nt] = f32x4{0.f, 0.f, 0.f, 0.f};

  auto pv = [&](const unsigned short* P, const unsigned short* V) {
    __builtin_amdgcn_s_setprio(1);
    #pragma unroll
    for (int ktq = 0; ktq < 2; ++ktq) {
      int prow = 16 * w + c;
      short8 pa = *(const short8*)((const char*)P + prow * 128 + ((ktq * 64 + g * 16) ^ ((prow & 7) << 4)));
      #pragma unroll
      for (int nt = 0; nt < 8; ++nt) {
        int vrow = nt * 16 + c;
        short8 vb = *(const short8*)((const char*)V + vrow * 128 + ((ktq * 64 + g * 16) ^ ((vrow & 7) << 4)));
        o[nt] = __builtin_amdgcn_mfma_f32_16x16x32_bf16(pa, vb, o[nt], 0, 0, 0);
      }
    }
    __builtin_amdgcn_s_setprio(0);
  };

  pv(L0, L2);                    // q0: Pq0 x VTq0
  __syncthreads();               // S3 (all waves done with L2)
  vt_write(rq3, L2);             // VTq3 -> L2
  pv(L0 + 64 * 128, L1);         // q1: Pq1 x VTq1

  #pragma unroll
  for (int r = 0; r < 4; ++r) {  // Pq2 -> L0a (wave-local reuse)
    int i = 16 * w + 4 * g + r;
    #pragma unroll
    for (int jt = 8; jt < 12; ++jt) {
      int jl = (jt - 8) * 16 + c;
      *(unsigned short*)((char*)L0 + i * 128 + ((jl * 2) ^ ((i & 7) << 4))) = f2bf(acc[jt][r]);
    }
  }
  pv(L0, L1 + 64 * 128);         // q2: Pq2 x VTq2

  #pragma unroll
  for (int r = 0; r < 4; ++r) {  // Pq3 -> L0b (wave-local reuse)
    int i = 16 * w + 4 * g + r;
    #pragma unroll
    for (int jt = 12; jt < 16; ++jt) {
      int jl = (jt - 12) * 16 + c;
      *(unsigned short*)((char*)(L0 + 64 * 128) + i * 128 + ((jl * 2) ^ ((i & 7) << 4))) = f2bf(acc[jt][r]);
    }
  }
  __syncthreads();               // S4 (VTq3 written by all waves)
  pv(L0 + 64 * 128, L2);         // q3: Pq3 x VTq3

  // ---- store (undo rotation) ----
  #pragma unroll
  for (int r = 0; r < 4; ++r) {
    int il = 4 * g + r;
    int t = u * BSZ_ + 16 * w + il;
    if (rot) t = (t + (BSZ_ - 1)) & (T_ - 1);
    float* orow = out + base + (size_t)t * DH_;
    #pragma unroll
    for (int nt = 0; nt < 8; ++nt) {
      orow[nt * 16 + c] = o[nt][r];
    }
  }
}

extern "C" void kernel_launch(void* const* d_in, const int* in_sizes, int n_in,
                              void* d_out, int out_size, void* d_ws, size_t ws_size,
                              hipStream_t stream) {
  const float* q = (const float*)d_in[0];
  const float* k = (const float*)d_in[1];
  const float* v = (const float*)d_in[2];
  const float* W = (const float*)d_in[3];
  float* out = (float*)d_out;

  float*  bucketsum = (float*)d_ws;               // 131072 floats
  float*  firstrow  = bucketsum + 131072;         // 131072 floats
  float2* scIdx     = (float2*)(firstrow + 131072); // 1024 float2

  k_bucket_sums<<<BH_ * NB_, 256, 0, stream>>>(k, bucketsum, firstrow);
  k_routing<<<BH_, 256, 0, stream>>>(W, bucketsum, firstrow, scIdx);
  k_attn<<<BH_ * NB_, 512, 0, stream>>>(q, k, v, scIdx, out);
}

// Round 4
// 92.674 us; speedup vs baseline: 1.3213x; 1.3213x over previous
//
#include <hip/hip_runtime.h>

// Problem constants
constexpr int T_    = 4096;
constexpr int DH_   = 128;
constexpr int NB_   = 32;    // buckets
constexpr int BSZ_  = 128;   // bucket size
constexpr int HH_   = 4;     // H/2 (rotated heads start here)
constexpr int H_    = 8;
constexpr int BH_   = 32;    // B*H

typedef __attribute__((ext_vector_type(8))) short short8;
typedef __attribute__((ext_vector_type(4))) float f32x4;

__device__ __forceinline__ unsigned int cvt_pk_bf16(float lo, float hi) {
  unsigned int r;
  asm("v_cvt_pk_bf16_f32 %0, %1, %2" : "=v"(r) : "v"(lo), "v"(hi));
  return r;
}
__device__ __forceinline__ unsigned short cvt1_bf16(float x) {
  unsigned int r;
  asm("v_cvt_pk_bf16_f32 %0, %1, %2" : "=v"(r) : "v"(x), "v"(x));
  return (unsigned short)r;
}

__device__ __forceinline__ unsigned short f2bf(float f) {
  unsigned int u = __float_as_uint(f);
  unsigned int r = (u + 0x7FFFu + ((u >> 16) & 1u)) >> 16;
  return (unsigned short)r;
}

// ---------------- Kernel A1: per-bucket column sums + first row of each bucket ----------
__global__ __launch_bounds__(256)
void k_bucket_sums(const float* __restrict__ k,
                   float* __restrict__ bucketsum,
                   float* __restrict__ firstrow) {
  __shared__ float4 red[8][32];
  int blk = blockIdx.x;           // (b*H + h)*NB + u
  int u = blk & (NB_ - 1);
  int bh = blk >> 5;
  int h = bh & (H_ - 1);
  bool rot = (h >= HH_);
  int tid = threadIdx.x;
  int rq = tid >> 5;              // 0..7
  int l  = tid & 31;              // 0..31
  int d0 = l * 4;
  const float* kb = k + (size_t)bh * T_ * DH_;

  float4 s = {0.f, 0.f, 0.f, 0.f};
  float4 first = {0.f, 0.f, 0.f, 0.f};
  #pragma unroll
  for (int it = 0; it < 16; ++it) {
    int i = it * 8 + rq;
    int t = u * BSZ_ + i;
    if (rot) t = (t + (BSZ_ - 1)) & (T_ - 1);
    float4 a = *(const float4*)(kb + (size_t)t * DH_ + d0);
    s.x += a.x; s.y += a.y; s.z += a.z; s.w += a.w;
    if (it == 0 && rq == 0) first = a;
  }
  red[rq][l] = s;
  __syncthreads();
  if (rq == 0) {
    float4 acc = {0.f, 0.f, 0.f, 0.f};
    #pragma unroll
    for (int j = 0; j < 8; ++j) {
      float4 a = red[j][l];
      acc.x += a.x; acc.y += a.y; acc.z += a.z; acc.w += a.w;
    }
    *(float4*)(bucketsum + (size_t)blk * DH_ + d0) = acc;
    *(float4*)(firstrow  + (size_t)blk * DH_ + d0) = first;
  }
}

// ---------------- Kernel A2: routing matrix R -> (scale, idx) packed float2 -------------
__global__ __launch_bounds__(256)
void k_routing(const float* __restrict__ W,
               const float* __restrict__ bucketsum,
               const float* __restrict__ firstrow,
               float2* __restrict__ scIdx) {
  __shared__ float Wl[2 * DH_ * NB_];      // [e][v] row-major, 8192 floats
  __shared__ float Xl[NB_][2 * DH_ + 1];   // padded
  __shared__ float Rl[NB_][36];            // 36-float rows: 16B aligned
  int bh = blockIdx.x;
  int h = bh & (H_ - 1);
  int tid = threadIdx.x;                   // 256 threads

  const float4* Wg = (const float4*)(W + (size_t)h * 2 * DH_ * NB_);
  #pragma unroll
  for (int rep = 0; rep < 8; ++rep)
    ((float4*)Wl)[tid + rep * 256] = Wg[tid + rep * 256];

  if (tid < DH_) {
    int d = tid;
    float S = 0.f;
    for (int u = 0; u < NB_; ++u) {
      float fr = firstrow [((size_t)bh * NB_ + u) * DH_ + d];
      float bs = bucketsum[((size_t)bh * NB_ + u) * DH_ + d];
      Xl[u][d]        = (S + fr) / (float)(u * BSZ_ + 1);
      Xl[u][DH_ + d]  = fr;
      S += bs;
    }
  }
  __syncthreads();

  {
    int u = tid >> 3;
    int vg = tid & 7;
    float4 racc = {0.f, 0.f, 0.f, 0.f};
    for (int e = 0; e < 2 * DH_; ++e) {
      float xv = Xl[u][e];
      float4 wv = *(const float4*)(Wl + e * NB_ + vg * 4);
      racc.x += xv * wv.x; racc.y += xv * wv.y;
      racc.z += xv * wv.z; racc.w += xv * wv.w;
    }
    racc.x = (racc.x > 0.f) ? racc.x : 0.01f * racc.x;
    racc.y = (racc.y > 0.f) ? racc.y : 0.01f * racc.y;
    racc.z = (racc.z > 0.f) ? racc.z : 0.01f * racc.z;
    racc.w = (racc.w > 0.f) ? racc.w : 0.01f * racc.w;
    *(float4*)(&Rl[u][vg * 4]) = racc;
  }
  __syncthreads();

  if (tid < NB_) {
    int u = tid;
    float m = -3.4e38f;
    float r[NB_];
    #pragma unroll
    for (int v = 0; v < NB_; ++v) { r[v] = Rl[u][v]; m = fmaxf(m, r[v]); }
    float Z = 0.f;
    #pragma unroll
    for (int v = 0; v < NB_; ++v) Z += expf(r[v] - m);
    float best = -3.4e38f; int bi = 0;
    for (int v = 0; v < u; ++v) {        // tril(-1): only v < u survive
      if (r[v] > best) { best = r[v]; bi = v; }
    }
    float sc = (u == 0) ? 0.f : expf(best - m) / Z;
    int  idx = (u == 0) ? 0 : bi;
    scIdx[bh * NB_ + u] = make_float2(sc, __int_as_float(idx));
  }
}

// ---------------- Kernel B: R2 structure + cvt_pk conversions + folded scales ----------
// RA 32KB: K1 -> P-half1 -> P-half2. RB 32KB: K2 -> VT-half1 -> VT-half2.
// sc folded into score scale (cols j<128) and into P values; staging is pure copy.
__global__ __launch_bounds__(512, 4)
void k_attn(const float* __restrict__ q, const float* __restrict__ k,
            const float* __restrict__ v, const float2* __restrict__ scIdx,
            float* __restrict__ out) {
  __shared__ __align__(16) unsigned short RA[128 * 128];   // 32KB
  __shared__ __align__(16) unsigned short RB[128 * 128];   // 32KB

  int blk0 = blockIdx.x;
  int blk  = ((blk0 & 7) << 7) | (blk0 >> 3);  // XCD-chunked swizzle (1024 = 8*128)
  int u  = blk & (NB_ - 1);
  int bh = blk >> 5;
  int h  = bh & (H_ - 1);
  bool rot = (h >= HH_);
  float2 si = scIdx[bh * NB_ + u];
  float sc = si.x;
  int  src = __float_as_int(si.y);
  const size_t base = (size_t)bh * T_ * DH_;

  int tid  = threadIdx.x;
  int lane = tid & 63;
  int w    = tid >> 6;        // wave 0..7, owns q-rows [16w, 16w+16)
  int g    = lane >> 4;       // 0..3
  int c    = lane & 15;       // 0..15

  // ---- Q fragments ----
  short8 qf[4];
  {
    int t = u * BSZ_ + 16 * w + c;
    if (rot) t = (t + (BSZ_ - 1)) & (T_ - 1);
    const float* qrow = q + base + (size_t)t * DH_;
    #pragma unroll
    for (int kt = 0; kt < 4; ++kt) {
      f32x4 a = *(const f32x4*)(qrow + kt * 32 + g * 8);
      f32x4 b = *(const f32x4*)(qrow + kt * 32 + g * 8 + 4);
      union { unsigned int u32[4]; short8 s; } U;
      U.u32[0] = cvt_pk_bf16(a[0], a[1]);
      U.u32[1] = cvt_pk_bf16(a[2], a[3]);
      U.u32[2] = cvt_pk_bf16(b[0], b[1]);
      U.u32[3] = cvt_pk_bf16(b[2], b[3]);
      qf[kt] = U.s;
    }
  }

  // ---- Stage K halves (pure copy-convert): K1->RA, K2->RB ----
  #pragma unroll
  for (int rep = 0; rep < 16; ++rep) {
    int chunk = tid + rep * 512;          // 8192 chunks of 4 floats
    int jr = chunk >> 5;                  // 0..255
    int c0 = (chunk & 31) * 4;
    int t = (jr < BSZ_) ? (src * BSZ_ + jr) : (u * BSZ_ + (jr - BSZ_));
    if (rot) t = (t + (BSZ_ - 1)) & (T_ - 1);
    f32x4 a = *(const f32x4*)(k + base + (size_t)t * DH_ + c0);
    uint2 wv;
    wv.x = cvt_pk_bf16(a[0], a[1]);
    wv.y = cvt_pk_bf16(a[2], a[3]);
    unsigned short* Rg = (jr < BSZ_) ? RA : RB;
    int row = jr & 127;
    *(uint2*)((char*)Rg + row * 256 + ((c0 * 2) ^ ((row & 15) << 4))) = wv;
  }
  __syncthreads();   // S1

  // ---- QK^T: 16 rows x 256 cols per wave ----
  f32x4 acc[16];
  #pragma unroll
  for (int jt = 0; jt < 16; ++jt) acc[jt] = f32x4{0.f, 0.f, 0.f, 0.f};

  __builtin_amdgcn_s_setprio(1);
  #pragma unroll
  for (int kt = 0; kt < 4; ++kt) {
    #pragma unroll
    for (int jt = 0; jt < 16; ++jt) {
      const unsigned short* Rg = (jt < 8) ? RA : RB;
      int row = (jt & 7) * 16 + c;
      short8 bfr = *(const short8*)((const char*)Rg + row * 256 + ((kt * 64 + g * 16) ^ ((row & 15) << 4)));
      acc[jt] = __builtin_amdgcn_mfma_f32_16x16x32_bf16(qf[kt], bfr, acc[jt], 0, 0, 0);
    }
  }
  __builtin_amdgcn_s_setprio(0);

  __syncthreads();   // S2 (K reads done; RA/RB free)

  // ---- mask + softmax (sc and log2e folded into score scales; exp2) ----
  const bool lastrot = rot && (u == NB_ - 1);
  const float LOG2E = 1.44269504f;
  float scale1 = 0.03125f * LOG2E * sc;   // cols j<128 (src bucket, R-weighted)
  float scale2 = 0.03125f * LOG2E;        // cols j>=128 (own bucket)
  #pragma unroll
  for (int r = 0; r < 4; ++r) {
    int i = 16 * w + 4 * g + r;
    float mx = -3.4e38f;
    #pragma unroll
    for (int jt = 0; jt < 16; ++jt) {
      int jb = (jt - 8) * 16 + c;          // j-128 for jt>=8
      float s = acc[jt][r] * ((jt < 8) ? scale1 : scale2);
      bool vis;
      if (jt < 8)       vis = !(lastrot && i > 0);                       // j<128: causal always; special kills i>0 on lastrot
      else if (jt == 8) vis = (i >= jb) && !(lastrot && c == 0 && i > 0); // j==128 is special on lastrot
      else              vis = (i >= jb);
      s = vis ? s : -3.4e38f;
      acc[jt][r] = s;
      mx = fmaxf(mx, s);
    }
    mx = fmaxf(mx, __shfl_xor(mx, 1));
    mx = fmaxf(mx, __shfl_xor(mx, 2));
    mx = fmaxf(mx, __shfl_xor(mx, 4));
    mx = fmaxf(mx, __shfl_xor(mx, 8));
    float zs = 0.f;
    #pragma unroll
    for (int jt = 0; jt < 16; ++jt) {
      float p = exp2f(acc[jt][r] - mx);
      acc[jt][r] = p;
      zs += p;
    }
    zs += __shfl_xor(zs, 1);
    zs += __shfl_xor(zs, 2);
    zs += __shfl_xor(zs, 4);
    zs += __shfl_xor(zs, 8);
    float rz = 1.f / zs;
    float rzs = rz * sc;                   // P cols j<128 carry sc into PV
    #pragma unroll
    for (int jt = 0; jt < 16; ++jt) acc[jt][r] *= (jt < 8) ? rzs : rz;
    #pragma unroll
    for (int jt = 0; jt < 8; ++jt) {
      int jc = jt * 16 + c;
      *(unsigned short*)((char*)RA + i * 256 + ((jc * 2) ^ ((i & 15) << 4))) = cvt1_bf16(acc[jt][r]);
    }
  }

  // ---- stage VT-half (pure copy-convert, transposed) into RB ----
  auto stageVT = [&](int sb) {
    #pragma unroll
    for (int rep = 0; rep < 2; ++rep) {
      int chunk = tid + rep * 512;        // 1024 4x4 tiles
      int dt = chunk & 31, j4 = chunk >> 5;
      int d0 = dt * 4, j0 = j4 * 4;
      f32x4 rr[4];
      #pragma unroll
      for (int jj = 0; jj < 4; ++jj) {
        int t = sb * BSZ_ + j0 + jj;
        if (rot) t = (t + (BSZ_ - 1)) & (T_ - 1);
        rr[jj] = *(const f32x4*)(v + base + (size_t)t * DH_ + d0);
      }
      #pragma unroll
      for (int m = 0; m < 4; ++m) {
        uint2 wv;
        wv.x = cvt_pk_bf16(rr[0][m], rr[1][m]);
        wv.y = cvt_pk_bf16(rr[2][m], rr[3][m]);
        int row = d0 + m;
        *(uint2*)((char*)RB + row * 256 + ((j0 * 2) ^ ((row & 15) << 4))) = wv;
      }
    }
  };
  stageVT(src);
  __syncthreads();   // S3

  // ---- PV halves ----
  f32x4 o[8];
  #pragma unroll
  for (int nt = 0; nt < 8; ++nt) o[nt] = f32x4{0.f, 0.f, 0.f, 0.f};

  auto pv = [&]() {
    __builtin_amdgcn_s_setprio(1);
    #pragma unroll
    for (int kt = 0; kt < 4; ++kt) {
      int prow = 16 * w + c;
      short8 pa = *(const short8*)((const char*)RA + prow * 256 + ((kt * 64 + g * 16) ^ ((prow & 15) << 4)));
      #pragma unroll
      for (int nt = 0; nt < 8; ++nt) {
        int vrow = nt * 16 + c;
        short8 vb = *(const short8*)((const char*)RB + vrow * 256 + ((kt * 64 + g * 16) ^ ((vrow & 15) << 4)));
        o[nt] = __builtin_amdgcn_mfma_f32_16x16x32_bf16(pa, vb, o[nt], 0, 0, 0);
      }
    }
    __builtin_amdgcn_s_setprio(0);
  };
  pv();              // half 1
  __syncthreads();   // S4

  // ---- P-half2 into RA, VT-half2 into RB ----
  #pragma unroll
  for (int r = 0; r < 4; ++r) {
    int i = 16 * w + 4 * g + r;
    #pragma unroll
    for (int jt = 8; jt < 16; ++jt) {
      int jc = (jt - 8) * 16 + c;
      *(unsigned short*)((char*)RA + i * 256 + ((jc * 2) ^ ((i & 15) << 4))) = cvt1_bf16(acc[jt][r]);
    }
  }
  stageVT(u);
  __syncthreads();   // S5

  pv();              // half 2

  // ---- store (undo rotation) ----
  #pragma unroll
  for (int r = 0; r < 4; ++r) {
    int il = 4 * g + r;
    int t = u * BSZ_ + 16 * w + il;
    if (rot) t = (t + (BSZ_ - 1)) & (T_ - 1);
    float* orow = out + base + (size_t)t * DH_;
    #pragma unroll
    for (int nt = 0; nt < 8; ++nt) {
      orow[nt * 16 + c] = o[nt][r];
    }
  }
}

extern "C" void kernel_launch(void* const* d_in, const int* in_sizes, int n_in,
                              void* d_out, int out_size, void* d_ws, size_t ws_size,
                              hipStream_t stream) {
  const float* q = (const float*)d_in[0];
  const float* k = (const float*)d_in[1];
  const float* v = (const float*)d_in[2];
  const float* W = (const float*)d_in[3];
  float* out = (float*)d_out;

  float*  bucketsum = (float*)d_ws;                 // 131072 floats
  float*  firstrow  = bucketsum + 131072;           // 131072 floats
  float2* scIdx     = (float2*)(firstrow + 131072); // 1024 float2

  k_bucket_sums<<<BH_ * NB_, 256, 0, stream>>>(k, bucketsum, firstrow);
  k_routing<<<BH_, 256, 0, stream>>>(W, bucketsum, firstrow, scIdx);
  k_attn<<<BH_ * NB_, 512, 0, stream>>>(q, k, v, scIdx, out);
}